// Round 1
// baseline (1093.129 us; speedup 1.0000x reference)
//
#include <hip/hip_runtime.h>

// AttnBlock2D: GroupNorm -> QKV 1x1conv -> 1-head attention (hw=4096, dh=512) -> proj + residual
// b=8, c=512, h=w=64. All heavy compute via bf16 MFMA (16x16x32), f32 accumulate.
//
// ws layout (bytes):
//   [0)            4*512*512*2      = 2MB   : wq,wk,wv,wp as bf16
//   [2MB)          8*32*2*4         = 2KB   : groupnorm (mean,rstd)
//   [2MB+4K)       8*4096*512*2     = 32MB  : h_t (hw,c) bf16   (aliased later as o_t)
//   +32MB                                    : q_t (hw,c)
//   +32MB                                    : k_t (hw,c)
//   +32MB                                    : v   (c,hw)
//   +G*32MB                                  : S/P (hw,hw) bf16, G batches at a time
// G adapts to ws_size (8 -> 4 -> 2 -> 1).

#define BATCH 8
#define CCH 512
#define HWP 4096
#define NG 32

typedef __attribute__((ext_vector_type(8))) short s16x8;
typedef __attribute__((ext_vector_type(4))) float f32x4;

__device__ __forceinline__ unsigned short f2bf(float f) {
  union { float f; unsigned u; } v; v.f = f;
  return (unsigned short)((v.u + 0x7FFFu + ((v.u >> 16) & 1u)) >> 16);
}
__device__ __forceinline__ float bf2f(unsigned short h) {
  union { unsigned u; float f; } v; v.u = ((unsigned)h) << 16;
  return v.f;
}

// ---------------- weight convert f32 -> bf16 (4 matrices) ----------------
__global__ void cvt_w(const float* __restrict__ w0, const float* __restrict__ w1,
                      const float* __restrict__ w2, const float* __restrict__ w3,
                      unsigned short* __restrict__ out) {
  int i = blockIdx.x * 256 + threadIdx.x;
  const int n = CCH * CCH;
  if (i < n) {
    out[i]         = f2bf(w0[i]);
    out[n + i]     = f2bf(w1[i]);
    out[2 * n + i] = f2bf(w2[i]);
    out[3 * n + i] = f2bf(w3[i]);
  }
}

// ---------------- GroupNorm stats: one block per (b,g) ----------------
__global__ void gn_stats(const float* __restrict__ x, float* __restrict__ stats) {
  const int bg = blockIdx.x;                     // b*32+g ; group data is contiguous 16*4096 f32
  const float* base = x + (size_t)bg * (16 * HWP);
  float s = 0.f, sq = 0.f;
  for (int i = threadIdx.x; i < 16 * HWP / 4; i += 256) {
    float4 v = ((const float4*)base)[i];
    s += v.x + v.y + v.z + v.w;
    sq += v.x * v.x + v.y * v.y + v.z * v.z + v.w * v.w;
  }
  #pragma unroll
  for (int o = 32; o; o >>= 1) { s += __shfl_xor(s, o); sq += __shfl_xor(sq, o); }
  __shared__ float ls[4], lq[4];
  const int wv = threadIdx.x >> 6;
  if ((threadIdx.x & 63) == 0) { ls[wv] = s; lq[wv] = sq; }
  __syncthreads();
  if (threadIdx.x == 0) {
    s = ls[0] + ls[1] + ls[2] + ls[3];
    sq = lq[0] + lq[1] + lq[2] + lq[3];
    const float inv_n = 1.f / (16.f * HWP);
    float mean = s * inv_n;
    float var = sq * inv_n - mean * mean;
    stats[2 * bg] = mean;
    stats[2 * bg + 1] = rsqrtf(var + 1e-5f);
  }
}

// ---------------- GroupNorm apply + transpose -> h_t (hw, c) bf16 ----------------
__global__ void gn_apply(const float* __restrict__ x, const float* __restrict__ stats,
                         const float* __restrict__ scale, const float* __restrict__ bias,
                         unsigned short* __restrict__ ht) {
  // grid (HWP/64, CCH/64, B), block 256
  const int p0 = blockIdx.x * 64, c0 = blockIdx.y * 64, b = blockIdx.z;
  const int tx = threadIdx.x & 63, ty = threadIdx.x >> 6;
  __shared__ unsigned short tile[64][65];
  #pragma unroll 4
  for (int j = 0; j < 16; ++j) {
    int cl = ty + j * 4;
    int c = c0 + cl;
    int g = c >> 4;
    float mean = stats[(b * NG + g) * 2];
    float rstd = stats[(b * NG + g) * 2 + 1];
    float v = x[((size_t)(b * CCH + c)) * HWP + p0 + tx];
    v = (v - mean) * rstd * scale[c] + bias[c];
    tile[cl][tx] = f2bf(v);
  }
  __syncthreads();
  #pragma unroll 4
  for (int j = 0; j < 16; ++j) {
    int pl = ty + j * 4;
    ht[((size_t)b * HWP + p0 + pl) * CCH + c0 + tx] = tile[tx][pl];
  }
}

// ---------------- NT GEMM: C[M,N] = scale * A[M,K] * B[N,K]^T (+biases, +residual) ----------------
// A,B bf16 k-contiguous. 128x128 tile, 4 waves, 16x16x32 MFMA, BK=64, global_load_lds staging.
__global__ __launch_bounds__(256)
void gemm_nt(const unsigned short* __restrict__ A,
             const unsigned short* __restrict__ Bm,
             void* __restrict__ Cm,
             const float* __restrict__ biasRow,
             const float* __restrict__ biasCol,
             const float* __restrict__ Res,
             int M, int N, int K, float scale, int outBf16,
             long long sA, long long sB, long long sC, long long sRes) {
  const int bz = blockIdx.z;
  const unsigned short* Ab = A + (size_t)bz * sA;
  const unsigned short* Bb = Bm + (size_t)bz * sB;
  const int m0 = blockIdx.y * 128, n0 = blockIdx.x * 128;
  __shared__ __align__(16) unsigned short lA[128 * 64];
  __shared__ __align__(16) unsigned short lB[128 * 64];
  const int tid = threadIdx.x, wave = tid >> 6, lane = tid & 63;
  const int wr = (wave >> 1) * 64, wc = (wave & 1) * 64;
  const int lr = lane & 15, lk = (lane >> 4) * 8;
  f32x4 acc[4][4] = {};

  const int chunkBase = wave * 64 + lane;
  for (int kt = 0; kt < K; kt += 64) {
    #pragma unroll
    for (int it = 0; it < 4; ++it) {
      int chunk = it * 256 + chunkBase;
      int row = chunk >> 3, c8 = (chunk & 7) * 8;
      __builtin_amdgcn_global_load_lds(
          (const __attribute__((address_space(1))) unsigned int*)(Ab + (size_t)(m0 + row) * K + kt + c8),
          (__attribute__((address_space(3))) unsigned int*)(lA + (size_t)(it * 256 + wave * 64) * 8),
          16, 0, 0);
    }
    #pragma unroll
    for (int it = 0; it < 4; ++it) {
      int chunk = it * 256 + chunkBase;
      int row = chunk >> 3, c8 = (chunk & 7) * 8;
      __builtin_amdgcn_global_load_lds(
          (const __attribute__((address_space(1))) unsigned int*)(Bb + (size_t)(n0 + row) * K + kt + c8),
          (__attribute__((address_space(3))) unsigned int*)(lB + (size_t)(it * 256 + wave * 64) * 8),
          16, 0, 0);
    }
    __syncthreads();
    #pragma unroll
    for (int kk = 0; kk < 64; kk += 32) {
      s16x8 af[4], bfv[4];
      #pragma unroll
      for (int m = 0; m < 4; ++m)
        af[m] = *(const s16x8*)&lA[(wr + m * 16 + lr) * 64 + kk + lk];
      #pragma unroll
      for (int n = 0; n < 4; ++n)
        bfv[n] = *(const s16x8*)&lB[(wc + n * 16 + lr) * 64 + kk + lk];
      #pragma unroll
      for (int m = 0; m < 4; ++m)
        #pragma unroll
        for (int n = 0; n < 4; ++n)
          acc[m][n] = __builtin_amdgcn_mfma_f32_16x16x32_bf16(af[m], bfv[n], acc[m][n], 0, 0, 0);
    }
    __syncthreads();
  }

  const int r0 = (lane >> 4) * 4, ccol = lane & 15;
  #pragma unroll
  for (int m = 0; m < 4; ++m) {
    const int gm = m0 + wr + m * 16 + r0;
    #pragma unroll
    for (int n = 0; n < 4; ++n) {
      const int gn = n0 + wc + n * 16 + ccol;
      float bc = biasCol ? biasCol[gn] : 0.f;
      #pragma unroll
      for (int r = 0; r < 4; ++r) {
        const int grow = gm + r;
        float val = acc[m][n][r] * scale + bc;
        if (biasRow) val += biasRow[grow];
        size_t idx = (size_t)grow * N + gn;
        if (Res) val += Res[(size_t)bz * sRes + idx];
        if (outBf16) ((unsigned short*)Cm)[(size_t)bz * sC + idx] = f2bf(val);
        else         ((float*)Cm)[(size_t)bz * sC + idx] = val;
      }
    }
  }
}

// ---------------- in-place row softmax on bf16 scores ----------------
__global__ void softmax_rows(unsigned short* __restrict__ S) {
  // grid (HWP, G); one block per row of 4096
  size_t roff = ((size_t)blockIdx.y * HWP + blockIdx.x) * HWP;
  unsigned short* row = S + roff;
  const int tid = threadIdx.x;
  float v[16];
  s16x8 rlo = *(const s16x8*)&row[tid * 16];
  s16x8 rhi = *(const s16x8*)&row[tid * 16 + 8];
  #pragma unroll
  for (int j = 0; j < 8; ++j) {
    v[j] = bf2f((unsigned short)rlo[j]);
    v[8 + j] = bf2f((unsigned short)rhi[j]);
  }
  float mx = v[0];
  #pragma unroll
  for (int j = 1; j < 16; ++j) mx = fmaxf(mx, v[j]);
  #pragma unroll
  for (int o = 32; o; o >>= 1) mx = fmaxf(mx, __shfl_xor(mx, o));
  __shared__ float red[8];
  const int wv = tid >> 6;
  if ((tid & 63) == 0) red[wv] = mx;
  __syncthreads();
  mx = fmaxf(fmaxf(red[0], red[1]), fmaxf(red[2], red[3]));
  float s = 0.f;
  #pragma unroll
  for (int j = 0; j < 16; ++j) { v[j] = __expf(v[j] - mx); s += v[j]; }
  #pragma unroll
  for (int o = 32; o; o >>= 1) s += __shfl_xor(s, o);
  if ((tid & 63) == 0) red[4 + wv] = s;
  __syncthreads();
  s = red[4] + red[5] + red[6] + red[7];
  float inv = 1.f / s;
  #pragma unroll
  for (int j = 0; j < 8; ++j) {
    rlo[j] = (short)f2bf(v[j] * inv);
    rhi[j] = (short)f2bf(v[8 + j] * inv);
  }
  *(s16x8*)&row[tid * 16] = rlo;
  *(s16x8*)&row[tid * 16 + 8] = rhi;
}

extern "C" void kernel_launch(void* const* d_in, const int* in_sizes, int n_in,
                              void* d_out, int out_size, void* d_ws, size_t ws_size,
                              hipStream_t stream) {
  (void)in_sizes; (void)n_in; (void)out_size;
  const float* x   = (const float*)d_in[0];
  const float* nsc = (const float*)d_in[1];
  const float* nbi = (const float*)d_in[2];
  const float* wq  = (const float*)d_in[3];
  const float* bq  = (const float*)d_in[4];
  const float* wk  = (const float*)d_in[5];
  const float* bk  = (const float*)d_in[6];
  const float* wv  = (const float*)d_in[7];
  const float* bv  = (const float*)d_in[8];
  const float* wp  = (const float*)d_in[9];
  const float* bp  = (const float*)d_in[10];
  float* out = (float*)d_out;
  char* ws = (char*)d_ws;

  const size_t nW = (size_t)CCH * CCH;
  unsigned short* wb = (unsigned short*)ws;
  float* stats = (float*)(ws + 4 * nW * 2);
  const size_t o_h = 4 * nW * 2 + 4096;
  const size_t bhc = (size_t)BATCH * HWP * CCH;       // elements per full tensor
  unsigned short* ht  = (unsigned short*)(ws + o_h);
  unsigned short* qt  = ht + bhc;
  unsigned short* kt_ = qt + bhc;
  unsigned short* vb  = kt_ + bhc;
  unsigned short* Sb  = vb + bhc;
  unsigned short* ot  = ht;                            // alias: h_t dead after V-GEMM
  const size_t o_S = o_h + 4 * bhc * 2;
  const size_t sS1 = (size_t)HWP * HWP;                // score elements per batch
  int G = 8;
  while (G > 1 && o_S + (size_t)G * sS1 * 2 > ws_size) G >>= 1;

  const long long sHC = (long long)HWP * CCH;          // 2M elements

  cvt_w<<<dim3((unsigned)((nW + 255) / 256)), dim3(256), 0, stream>>>(wq, wk, wv, wp, wb);
  gn_stats<<<dim3(BATCH * NG), dim3(256), 0, stream>>>(x, stats);
  gn_apply<<<dim3(HWP / 64, CCH / 64, BATCH), dim3(256), 0, stream>>>(x, stats, nsc, nbi, ht);

  // Q: q_t[p][o] = sum_c h_t[p][c] wq[o][c] + bq[o]
  gemm_nt<<<dim3(CCH / 128, HWP / 128, BATCH), dim3(256), 0, stream>>>(
      ht, wb + 0 * nW, qt, nullptr, bq, nullptr, HWP, CCH, CCH, 1.f, 1, sHC, 0, sHC, 0);
  // K
  gemm_nt<<<dim3(CCH / 128, HWP / 128, BATCH), dim3(256), 0, stream>>>(
      ht, wb + 1 * nW, kt_, nullptr, bk, nullptr, HWP, CCH, CCH, 1.f, 1, sHC, 0, sHC, 0);
  // V: v[o][p] = sum_c wv[o][c] h_t[p][c] + bv[o]   (stored (c, hw))
  gemm_nt<<<dim3(HWP / 128, CCH / 128, BATCH), dim3(256), 0, stream>>>(
      wb + 2 * nW, ht, vb, bv, nullptr, nullptr, CCH, HWP, CCH, 1.f, 1, 0, sHC, sHC, 0);

  const float sc = 0.04419417382415922f;               // 512^-0.5
  for (int b0 = 0; b0 < BATCH; b0 += G) {
    // S[d][e] = scale * sum_c q_t[d][c] k_t[e][c]
    gemm_nt<<<dim3(HWP / 128, HWP / 128, G), dim3(256), 0, stream>>>(
        qt + (size_t)b0 * sHC, kt_ + (size_t)b0 * sHC, Sb, nullptr, nullptr, nullptr,
        HWP, HWP, CCH, sc, 1, sHC, sHC, (long long)HWP * HWP, 0);
    softmax_rows<<<dim3(HWP, G), dim3(256), 0, stream>>>(Sb);
    // o_t[d][c] = sum_e P[d][e] v[c][e]
    gemm_nt<<<dim3(CCH / 128, HWP / 128, G), dim3(256), 0, stream>>>(
        Sb, vb + (size_t)b0 * sHC, ot + (size_t)b0 * sHC, nullptr, nullptr, nullptr,
        HWP, CCH, HWP, 1.f, 1, (long long)HWP * HWP, sHC, sHC, 0);
  }

  // final: out[o][p] = x[o][p] + bp[o] + sum_c wp[o][c] o_t[p][c]   (f32 out)
  gemm_nt<<<dim3(HWP / 128, CCH / 128, BATCH), dim3(256), 0, stream>>>(
      wb + 3 * nW, ot, out, bp, nullptr, x, CCH, HWP, CCH, 1.f, 0, 0, sHC, sHC, sHC);
}

// Round 2
// 947.928 us; speedup vs baseline: 1.1532x; 1.1532x over previous
//
#include <hip/hip_runtime.h>

// AttnBlock2D: GroupNorm -> QKV 1x1conv -> 1-head attention (hw=4096, dh=512) -> proj + residual
// b=8, c=512, h=w=64. bf16 MFMA (16x16x32), f32 accumulate.
// R2: gemm_nt gets (1) double-buffered 2-phase K-loop (stage t+1 before compute t,
//     single barrier/iter), (2) bijective XCD swizzle (each XCD owns one batch),
//     (3) T2 LDS XOR swizzle applied BOTH at staging source and ds_read (rule #21).

#define BATCH 8
#define CCH 512
#define HWP 4096
#define NG 32

typedef __attribute__((ext_vector_type(8))) short s16x8;
typedef __attribute__((ext_vector_type(4))) float f32x4;

__device__ __forceinline__ unsigned short f2bf(float f) {
  union { float f; unsigned u; } v; v.f = f;
  return (unsigned short)((v.u + 0x7FFFu + ((v.u >> 16) & 1u)) >> 16);
}
__device__ __forceinline__ float bf2f(unsigned short h) {
  union { unsigned u; float f; } v; v.u = ((unsigned)h) << 16;
  return v.f;
}

// ---------------- weight convert f32 -> bf16 (4 matrices) ----------------
__global__ void cvt_w(const float* __restrict__ w0, const float* __restrict__ w1,
                      const float* __restrict__ w2, const float* __restrict__ w3,
                      unsigned short* __restrict__ out) {
  int i = blockIdx.x * 256 + threadIdx.x;
  const int n = CCH * CCH;
  if (i < n) {
    out[i]         = f2bf(w0[i]);
    out[n + i]     = f2bf(w1[i]);
    out[2 * n + i] = f2bf(w2[i]);
    out[3 * n + i] = f2bf(w3[i]);
  }
}

// ---------------- GroupNorm stats: one block per (b,g) ----------------
__global__ void gn_stats(const float* __restrict__ x, float* __restrict__ stats) {
  const int bg = blockIdx.x;                     // b*32+g ; group data contiguous 16*4096 f32
  const float* base = x + (size_t)bg * (16 * HWP);
  float s = 0.f, sq = 0.f;
  for (int i = threadIdx.x; i < 16 * HWP / 4; i += 256) {
    float4 v = ((const float4*)base)[i];
    s += v.x + v.y + v.z + v.w;
    sq += v.x * v.x + v.y * v.y + v.z * v.z + v.w * v.w;
  }
  #pragma unroll
  for (int o = 32; o; o >>= 1) { s += __shfl_xor(s, o); sq += __shfl_xor(sq, o); }
  __shared__ float ls[4], lq[4];
  const int wv = threadIdx.x >> 6;
  if ((threadIdx.x & 63) == 0) { ls[wv] = s; lq[wv] = sq; }
  __syncthreads();
  if (threadIdx.x == 0) {
    s = ls[0] + ls[1] + ls[2] + ls[3];
    sq = lq[0] + lq[1] + lq[2] + lq[3];
    const float inv_n = 1.f / (16.f * HWP);
    float mean = s * inv_n;
    float var = sq * inv_n - mean * mean;
    stats[2 * bg] = mean;
    stats[2 * bg + 1] = rsqrtf(var + 1e-5f);
  }
}

// ---------------- GroupNorm apply + transpose -> h_t (hw, c) bf16 ----------------
__global__ void gn_apply(const float* __restrict__ x, const float* __restrict__ stats,
                         const float* __restrict__ scale, const float* __restrict__ bias,
                         unsigned short* __restrict__ ht) {
  // grid (HWP/64, CCH/64, B), block 256
  const int p0 = blockIdx.x * 64, c0 = blockIdx.y * 64, b = blockIdx.z;
  const int tx = threadIdx.x & 63, ty = threadIdx.x >> 6;
  __shared__ unsigned short tile[64][65];
  #pragma unroll 4
  for (int j = 0; j < 16; ++j) {
    int cl = ty + j * 4;
    int c = c0 + cl;
    int g = c >> 4;
    float mean = stats[(b * NG + g) * 2];
    float rstd = stats[(b * NG + g) * 2 + 1];
    float v = x[((size_t)(b * CCH + c)) * HWP + p0 + tx];
    v = (v - mean) * rstd * scale[c] + bias[c];
    tile[cl][tx] = f2bf(v);
  }
  __syncthreads();
  #pragma unroll 4
  for (int j = 0; j < 16; ++j) {
    int pl = ty + j * 4;
    ht[((size_t)b * HWP + p0 + pl) * CCH + c0 + tx] = tile[tx][pl];
  }
}

// ---------------- NT GEMM: C[M,N] = scale * A[M,K] * B[N,K]^T (+biases, +residual) ----------------
// 128x128 tile, 4 waves, 16x16x32 MFMA, BK=64.
// Double-buffered LDS; global_load_lds staging with pre-swizzled source so that
// LDS chunk (row, c) holds global chunk (row, c^(row&7)); ds_read applies same XOR.
__global__ __launch_bounds__(256)
void gemm_nt(const unsigned short* __restrict__ A,
             const unsigned short* __restrict__ Bm,
             void* __restrict__ Cm,
             const float* __restrict__ biasRow,
             const float* __restrict__ biasCol,
             const float* __restrict__ Res,
             int M, int N, int K, float scale, int outBf16,
             long long sA, long long sB, long long sC, long long sRes) {
  // --- bijective XCD swizzle: physical lin -> logical block id ---
  const int nbx = gridDim.x, nby = gridDim.y;
  const int nb = nbx * nby * gridDim.z;
  int lin = (blockIdx.z * nby + blockIdx.y) * nbx + blockIdx.x;
  int bx, by, bz;
  if ((nb & 7) == 0) {
    int logical = (lin & 7) * (nb >> 3) + (lin >> 3);
    bx = logical % nbx;
    int t = logical / nbx;
    by = t % nby;
    bz = t / nby;
  } else { bx = blockIdx.x; by = blockIdx.y; bz = blockIdx.z; }

  const unsigned short* Ab = A + (size_t)bz * sA;
  const unsigned short* Bb = Bm + (size_t)bz * sB;
  const int m0 = by * 128, n0 = bx * 128;
  __shared__ __align__(16) unsigned short lA[2][128 * 64];
  __shared__ __align__(16) unsigned short lB[2][128 * 64];
  const int tid = threadIdx.x, wave = tid >> 6, lane = tid & 63;
  const int wr = (wave >> 1) * 64, wc = (wave & 1) * 64;
  const int lr = lane & 15, lkc = lane >> 4;          // lkc = k-chunk index 0..3
  f32x4 acc[4][4] = {};

  const int chunkBase = wave * 64 + lane;             // 0..255
  // per-lane staging address components (source column pre-swizzled: T2 both-sides rule)
  int srow[4], sc8[4];
  #pragma unroll
  for (int it = 0; it < 4; ++it) {
    int chunk = it * 256 + chunkBase;
    srow[it] = chunk >> 3;
    sc8[it] = (((chunk & 7) ^ (srow[it] & 7)) * 8);
  }

  #define STAGE(buf, kt)                                                                 \
    {                                                                                    \
      _Pragma("unroll")                                                                  \
      for (int it = 0; it < 4; ++it) {                                                   \
        __builtin_amdgcn_global_load_lds(                                                \
            (const __attribute__((address_space(1))) unsigned int*)(Ab + (size_t)(m0 + srow[it]) * K + (kt) + sc8[it]), \
            (__attribute__((address_space(3))) unsigned int*)(&lA[buf][0] + (size_t)(it * 256 + wave * 64) * 8),        \
            16, 0, 0);                                                                   \
        __builtin_amdgcn_global_load_lds(                                                \
            (const __attribute__((address_space(1))) unsigned int*)(Bb + (size_t)(n0 + srow[it]) * K + (kt) + sc8[it]), \
            (__attribute__((address_space(3))) unsigned int*)(&lB[buf][0] + (size_t)(it * 256 + wave * 64) * 8),        \
            16, 0, 0);                                                                   \
      }                                                                                  \
    }

  STAGE(0, 0);
  __syncthreads();
  int cur = 0;
  for (int kt = 0; kt < K; kt += 64) {
    if (kt + 64 < K) STAGE(cur ^ 1, kt + 64);
    #pragma unroll
    for (int kk = 0; kk < 64; kk += 32) {
      const int jbase = (kk >> 3) + lkc;              // global k-chunk 0..7 within row
      s16x8 af[4], bfv[4];
      #pragma unroll
      for (int m = 0; m < 4; ++m) {
        int r = wr + m * 16 + lr;
        af[m] = *(const s16x8*)&lA[cur][r * 64 + ((jbase ^ (r & 7)) << 3)];
      }
      #pragma unroll
      for (int n = 0; n < 4; ++n) {
        int r = wc + n * 16 + lr;
        bfv[n] = *(const s16x8*)&lB[cur][r * 64 + ((jbase ^ (r & 7)) << 3)];
      }
      #pragma unroll
      for (int m = 0; m < 4; ++m)
        #pragma unroll
        for (int n = 0; n < 4; ++n)
          acc[m][n] = __builtin_amdgcn_mfma_f32_16x16x32_bf16(af[m], bfv[n], acc[m][n], 0, 0, 0);
    }
    __syncthreads();
    cur ^= 1;
  }
  #undef STAGE

  const int r0 = (lane >> 4) * 4, ccol = lane & 15;
  #pragma unroll
  for (int m = 0; m < 4; ++m) {
    const int gm = m0 + wr + m * 16 + r0;
    #pragma unroll
    for (int n = 0; n < 4; ++n) {
      const int gn = n0 + wc + n * 16 + ccol;
      float bc = biasCol ? biasCol[gn] : 0.f;
      #pragma unroll
      for (int r = 0; r < 4; ++r) {
        const int grow = gm + r;
        float val = acc[m][n][r] * scale + bc;
        if (biasRow) val += biasRow[grow];
        size_t idx = (size_t)grow * N + gn;
        if (Res) val += Res[(size_t)bz * sRes + idx];
        if (outBf16) ((unsigned short*)Cm)[(size_t)bz * sC + idx] = f2bf(val);
        else         ((float*)Cm)[(size_t)bz * sC + idx] = val;
      }
    }
  }
}

// ---------------- in-place row softmax on bf16 scores ----------------
__global__ void softmax_rows(unsigned short* __restrict__ S) {
  // grid (HWP, G); one block per row of 4096
  size_t roff = ((size_t)blockIdx.y * HWP + blockIdx.x) * HWP;
  unsigned short* row = S + roff;
  const int tid = threadIdx.x;
  float v[16];
  s16x8 rlo = *(const s16x8*)&row[tid * 16];
  s16x8 rhi = *(const s16x8*)&row[tid * 16 + 8];
  #pragma unroll
  for (int j = 0; j < 8; ++j) {
    v[j] = bf2f((unsigned short)rlo[j]);
    v[8 + j] = bf2f((unsigned short)rhi[j]);
  }
  float mx = v[0];
  #pragma unroll
  for (int j = 1; j < 16; ++j) mx = fmaxf(mx, v[j]);
  #pragma unroll
  for (int o = 32; o; o >>= 1) mx = fmaxf(mx, __shfl_xor(mx, o));
  __shared__ float red[8];
  const int wv = tid >> 6;
  if ((tid & 63) == 0) red[wv] = mx;
  __syncthreads();
  mx = fmaxf(fmaxf(red[0], red[1]), fmaxf(red[2], red[3]));
  float s = 0.f;
  #pragma unroll
  for (int j = 0; j < 16; ++j) { v[j] = __expf(v[j] - mx); s += v[j]; }
  #pragma unroll
  for (int o = 32; o; o >>= 1) s += __shfl_xor(s, o);
  if ((tid & 63) == 0) red[4 + wv] = s;
  __syncthreads();
  s = red[4] + red[5] + red[6] + red[7];
  float inv = 1.f / s;
  #pragma unroll
  for (int j = 0; j < 8; ++j) {
    rlo[j] = (short)f2bf(v[j] * inv);
    rhi[j] = (short)f2bf(v[8 + j] * inv);
  }
  *(s16x8*)&row[tid * 16] = rlo;
  *(s16x8*)&row[tid * 16 + 8] = rhi;
}

extern "C" void kernel_launch(void* const* d_in, const int* in_sizes, int n_in,
                              void* d_out, int out_size, void* d_ws, size_t ws_size,
                              hipStream_t stream) {
  (void)in_sizes; (void)n_in; (void)out_size;
  const float* x   = (const float*)d_in[0];
  const float* nsc = (const float*)d_in[1];
  const float* nbi = (const float*)d_in[2];
  const float* wq  = (const float*)d_in[3];
  const float* bq  = (const float*)d_in[4];
  const float* wk  = (const float*)d_in[5];
  const float* bk  = (const float*)d_in[6];
  const float* wv  = (const float*)d_in[7];
  const float* bv  = (const float*)d_in[8];
  const float* wp  = (const float*)d_in[9];
  const float* bp  = (const float*)d_in[10];
  float* out = (float*)d_out;
  char* ws = (char*)d_ws;

  const size_t nW = (size_t)CCH * CCH;
  unsigned short* wb = (unsigned short*)ws;
  float* stats = (float*)(ws + 4 * nW * 2);
  const size_t o_h = 4 * nW * 2 + 4096;
  const size_t bhc = (size_t)BATCH * HWP * CCH;       // elements per full tensor
  unsigned short* ht  = (unsigned short*)(ws + o_h);
  unsigned short* qt  = ht + bhc;
  unsigned short* kt_ = qt + bhc;
  unsigned short* vb  = kt_ + bhc;
  unsigned short* Sb  = vb + bhc;
  unsigned short* ot  = ht;                            // alias: h_t dead after V-GEMM
  const size_t o_S = o_h + 4 * bhc * 2;
  const size_t sS1 = (size_t)HWP * HWP;                // score elements per batch
  int G = 8;
  while (G > 1 && o_S + (size_t)G * sS1 * 2 > ws_size) G >>= 1;

  const long long sHC = (long long)HWP * CCH;          // 2M elements

  cvt_w<<<dim3((unsigned)((nW + 255) / 256)), dim3(256), 0, stream>>>(wq, wk, wv, wp, wb);
  gn_stats<<<dim3(BATCH * NG), dim3(256), 0, stream>>>(x, stats);
  gn_apply<<<dim3(HWP / 64, CCH / 64, BATCH), dim3(256), 0, stream>>>(x, stats, nsc, nbi, ht);

  // Q: q_t[p][o] = sum_c h_t[p][c] wq[o][c] + bq[o]
  gemm_nt<<<dim3(CCH / 128, HWP / 128, BATCH), dim3(256), 0, stream>>>(
      ht, wb + 0 * nW, qt, nullptr, bq, nullptr, HWP, CCH, CCH, 1.f, 1, sHC, 0, sHC, 0);
  // K
  gemm_nt<<<dim3(CCH / 128, HWP / 128, BATCH), dim3(256), 0, stream>>>(
      ht, wb + 1 * nW, kt_, nullptr, bk, nullptr, HWP, CCH, CCH, 1.f, 1, sHC, 0, sHC, 0);
  // V: v[o][p] = sum_c wv[o][c] h_t[p][c] + bv[o]   (stored (c, hw))
  gemm_nt<<<dim3(HWP / 128, CCH / 128, BATCH), dim3(256), 0, stream>>>(
      wb + 2 * nW, ht, vb, bv, nullptr, nullptr, CCH, HWP, CCH, 1.f, 1, 0, sHC, sHC, 0);

  const float sc = 0.04419417382415922f;               // 512^-0.5
  for (int b0 = 0; b0 < BATCH; b0 += G) {
    // S[d][e] = scale * sum_c q_t[d][c] k_t[e][c]
    gemm_nt<<<dim3(HWP / 128, HWP / 128, G), dim3(256), 0, stream>>>(
        qt + (size_t)b0 * sHC, kt_ + (size_t)b0 * sHC, Sb, nullptr, nullptr, nullptr,
        HWP, HWP, CCH, sc, 1, sHC, sHC, (long long)HWP * HWP, 0);
    softmax_rows<<<dim3(HWP, G), dim3(256), 0, stream>>>(Sb);
    // o_t[d][c] = sum_e P[d][e] v[c][e]
    gemm_nt<<<dim3(CCH / 128, HWP / 128, G), dim3(256), 0, stream>>>(
        Sb, vb + (size_t)b0 * sHC, ot + (size_t)b0 * sHC, nullptr, nullptr, nullptr,
        HWP, CCH, HWP, 1.f, 1, (long long)HWP * HWP, sHC, sHC, 0);
  }

  // final: out[o][p] = x[o][p] + bp[o] + sum_c wp[o][c] o_t[p][c]   (f32 out)
  gemm_nt<<<dim3(HWP / 128, CCH / 128, BATCH), dim3(256), 0, stream>>>(
      wb + 3 * nW, ot, out, bp, nullptr, x, CCH, HWP, CCH, 1.f, 0, 0, sHC, sHC, sHC);
}

// Round 3
// 826.272 us; speedup vs baseline: 1.3230x; 1.1472x over previous
//
#include <hip/hip_runtime.h>

// AttnBlock2D: GroupNorm -> fused QKV 1x1conv -> 1-head attention (hw=4096, dh=512) -> proj + residual
// b=8, c=512, h=w=64. bf16 MFMA (16x16x32), f32 accumulate.
// R3: (1) Q,K,V fused into one N=1536 GEMM (lda/ldb/ldc strides added), V transposed
//     by a dedicated LDS-tile transpose kernel; (2) final GEMM gets a coalesced f32
//     epilogue (LDS bounce + float4 residual/store); (3) gemm instances tagged
//     template<int TAG> so rocprof names distinguish them.

#define BATCH 8
#define CCH 512
#define HWP 4096
#define NG 32

typedef __attribute__((ext_vector_type(8))) short s16x8;
typedef __attribute__((ext_vector_type(4))) float f32x4;

__device__ __forceinline__ unsigned short f2bf(float f) {
  union { float f; unsigned u; } v; v.f = f;
  return (unsigned short)((v.u + 0x7FFFu + ((v.u >> 16) & 1u)) >> 16);
}
__device__ __forceinline__ float bf2f(unsigned short h) {
  union { unsigned u; float f; } v; v.u = ((unsigned)h) << 16;
  return v.f;
}

// ---------------- weight convert f32 -> bf16 (4 matrices) + qkv bias concat ----------------
__global__ void cvt_w(const float* __restrict__ w0, const float* __restrict__ w1,
                      const float* __restrict__ w2, const float* __restrict__ w3,
                      const float* __restrict__ bq, const float* __restrict__ bk,
                      const float* __restrict__ bv,
                      unsigned short* __restrict__ out, float* __restrict__ bcat) {
  int i = blockIdx.x * 256 + threadIdx.x;
  const int n = CCH * CCH;
  if (i < CCH) {
    bcat[i]           = bq[i];
    bcat[CCH + i]     = bk[i];
    bcat[2 * CCH + i] = bv[i];
  }
  if (i < n) {
    out[i]         = f2bf(w0[i]);
    out[n + i]     = f2bf(w1[i]);
    out[2 * n + i] = f2bf(w2[i]);
    out[3 * n + i] = f2bf(w3[i]);
  }
}

// ---------------- GroupNorm stats: one block per (b,g) ----------------
__global__ void gn_stats(const float* __restrict__ x, float* __restrict__ stats) {
  const int bg = blockIdx.x;                     // b*32+g ; group data contiguous 16*4096 f32
  const float* base = x + (size_t)bg * (16 * HWP);
  float s = 0.f, sq = 0.f;
  for (int i = threadIdx.x; i < 16 * HWP / 4; i += 256) {
    float4 v = ((const float4*)base)[i];
    s += v.x + v.y + v.z + v.w;
    sq += v.x * v.x + v.y * v.y + v.z * v.z + v.w * v.w;
  }
  #pragma unroll
  for (int o = 32; o; o >>= 1) { s += __shfl_xor(s, o); sq += __shfl_xor(sq, o); }
  __shared__ float ls[4], lq[4];
  const int wv = threadIdx.x >> 6;
  if ((threadIdx.x & 63) == 0) { ls[wv] = s; lq[wv] = sq; }
  __syncthreads();
  if (threadIdx.x == 0) {
    s = ls[0] + ls[1] + ls[2] + ls[3];
    sq = lq[0] + lq[1] + lq[2] + lq[3];
    const float inv_n = 1.f / (16.f * HWP);
    float mean = s * inv_n;
    float var = sq * inv_n - mean * mean;
    stats[2 * bg] = mean;
    stats[2 * bg + 1] = rsqrtf(var + 1e-5f);
  }
}

// ---------------- GroupNorm apply + transpose -> h_t (hw, c) bf16 ----------------
__global__ void gn_apply(const float* __restrict__ x, const float* __restrict__ stats,
                         const float* __restrict__ scale, const float* __restrict__ bias,
                         unsigned short* __restrict__ ht) {
  // grid (HWP/64, CCH/64, B), block 256
  const int p0 = blockIdx.x * 64, c0 = blockIdx.y * 64, b = blockIdx.z;
  const int tx = threadIdx.x & 63, ty = threadIdx.x >> 6;
  __shared__ unsigned short tile[64][65];
  #pragma unroll 4
  for (int j = 0; j < 16; ++j) {
    int cl = ty + j * 4;
    int c = c0 + cl;
    int g = c >> 4;
    float mean = stats[(b * NG + g) * 2];
    float rstd = stats[(b * NG + g) * 2 + 1];
    float v = x[((size_t)(b * CCH + c)) * HWP + p0 + tx];
    v = (v - mean) * rstd * scale[c] + bias[c];
    tile[cl][tx] = f2bf(v);
  }
  __syncthreads();
  #pragma unroll 4
  for (int j = 0; j < 16; ++j) {
    int pl = ty + j * 4;
    ht[((size_t)b * HWP + p0 + pl) * CCH + c0 + tx] = tile[tx][pl];
  }
}

// ---------------- V transpose: qkv (b, p, 1536)[cols 1024:1536) -> vT (b, c, p) ----------------
__global__ void transpose_v(const unsigned short* __restrict__ qkv,
                            unsigned short* __restrict__ vT) {
  // grid (HWP/64, CCH/64, B)
  const int p0 = blockIdx.x * 64, c0 = blockIdx.y * 64, b = blockIdx.z;
  const int tx = threadIdx.x & 63, ty = threadIdx.x >> 6;
  __shared__ unsigned short tile[64][65];
  #pragma unroll 4
  for (int j = 0; j < 16; ++j) {
    int pl = ty + j * 4;
    tile[pl][tx] = qkv[((size_t)b * HWP + p0 + pl) * 1536 + 1024 + c0 + tx];
  }
  __syncthreads();
  #pragma unroll 4
  for (int j = 0; j < 16; ++j) {
    int cl = ty + j * 4;
    vT[((size_t)b * CCH + c0 + cl) * HWP + p0 + tx] = tile[tx][cl];
  }
}

// ---------------- NT GEMM: C[M,N] = scale * A[M,K] * B[N,K]^T (+biases, +residual) ----------------
// 128x128 tile, 4 waves, 16x16x32 MFMA, BK=64. Double-buffered LDS; pre-swizzled
// global_load_lds staging + XOR-swizzled ds_read (T2 both-sides). Bijective XCD swizzle.
// outBf16==0: coalesced f32 epilogue via LDS bounce (residual added there).
template<int TAG>
__global__ __launch_bounds__(256)
void gemm_nt(const unsigned short* __restrict__ A,
             const unsigned short* __restrict__ Bm,
             void* __restrict__ Cm,
             const float* __restrict__ biasRow,
             const float* __restrict__ biasCol,
             const float* __restrict__ Res,
             int M, int N, int K, int lda, int ldb, int ldc,
             float scale, int outBf16,
             long long sA, long long sB, long long sC, long long sRes) {
  // --- bijective XCD swizzle ---
  const int nbx = gridDim.x, nby = gridDim.y;
  const int nb = nbx * nby * gridDim.z;
  int lin = (blockIdx.z * nby + blockIdx.y) * nbx + blockIdx.x;
  int bx, by, bz;
  if ((nb & 7) == 0) {
    int logical = (lin & 7) * (nb >> 3) + (lin >> 3);
    bx = logical % nbx;
    int t = logical / nbx;
    by = t % nby;
    bz = t / nby;
  } else { bx = blockIdx.x; by = blockIdx.y; bz = blockIdx.z; }

  const unsigned short* Ab = A + (size_t)bz * sA;
  const unsigned short* Bb = Bm + (size_t)bz * sB;
  const int m0 = by * 128, n0 = bx * 128;
  __shared__ __align__(16) unsigned short sm[2][2][128 * 64];  // [A/B][dbuf][tile]
  const int tid = threadIdx.x, wave = tid >> 6, lane = tid & 63;
  const int wr = (wave >> 1) * 64, wc = (wave & 1) * 64;
  const int lr = lane & 15, lkc = lane >> 4;
  f32x4 acc[4][4] = {};

  const int chunkBase = wave * 64 + lane;             // 0..255
  int srow[4], sc8[4];
  #pragma unroll
  for (int it = 0; it < 4; ++it) {
    int chunk = it * 256 + chunkBase;
    srow[it] = chunk >> 3;
    sc8[it] = (((chunk & 7) ^ (srow[it] & 7)) * 8);
  }

  #define STAGE(buf, kt)                                                                 \
    {                                                                                    \
      _Pragma("unroll")                                                                  \
      for (int it = 0; it < 4; ++it) {                                                   \
        __builtin_amdgcn_global_load_lds(                                                \
            (const __attribute__((address_space(1))) unsigned int*)(Ab + (size_t)(m0 + srow[it]) * lda + (kt) + sc8[it]), \
            (__attribute__((address_space(3))) unsigned int*)(&sm[0][buf][0] + (size_t)(it * 256 + wave * 64) * 8),       \
            16, 0, 0);                                                                   \
        __builtin_amdgcn_global_load_lds(                                                \
            (const __attribute__((address_space(1))) unsigned int*)(Bb + (size_t)(n0 + srow[it]) * ldb + (kt) + sc8[it]), \
            (__attribute__((address_space(3))) unsigned int*)(&sm[1][buf][0] + (size_t)(it * 256 + wave * 64) * 8),       \
            16, 0, 0);                                                                   \
      }                                                                                  \
    }

  STAGE(0, 0);
  __syncthreads();
  int cur = 0;
  for (int kt = 0; kt < K; kt += 64) {
    if (kt + 64 < K) STAGE(cur ^ 1, kt + 64);
    #pragma unroll
    for (int kk = 0; kk < 64; kk += 32) {
      const int jbase = (kk >> 3) + lkc;
      s16x8 af[4], bfv[4];
      #pragma unroll
      for (int m = 0; m < 4; ++m) {
        int r = wr + m * 16 + lr;
        af[m] = *(const s16x8*)&sm[0][cur][r * 64 + ((jbase ^ (r & 7)) << 3)];
      }
      #pragma unroll
      for (int n = 0; n < 4; ++n) {
        int r = wc + n * 16 + lr;
        bfv[n] = *(const s16x8*)&sm[1][cur][r * 64 + ((jbase ^ (r & 7)) << 3)];
      }
      #pragma unroll
      for (int m = 0; m < 4; ++m)
        #pragma unroll
        for (int n = 0; n < 4; ++n)
          acc[m][n] = __builtin_amdgcn_mfma_f32_16x16x32_bf16(af[m], bfv[n], acc[m][n], 0, 0, 0);
    }
    __syncthreads();
    cur ^= 1;
  }
  #undef STAGE

  if (outBf16) {
    const int r0 = (lane >> 4) * 4, ccol = lane & 15;
    #pragma unroll
    for (int m = 0; m < 4; ++m) {
      const int gm = m0 + wr + m * 16 + r0;
      #pragma unroll
      for (int n = 0; n < 4; ++n) {
        const int gn = n0 + wc + n * 16 + ccol;
        float bc = biasCol ? biasCol[gn] : 0.f;
        #pragma unroll
        for (int r = 0; r < 4; ++r) {
          const int grow = gm + r;
          float val = acc[m][n][r] * scale + bc;
          if (biasRow) val += biasRow[grow];
          size_t idx = (size_t)grow * ldc + gn;
          ((unsigned short*)Cm)[(size_t)bz * sC + idx] = f2bf(val);
        }
      }
    }
  } else {
    // coalesced f32 epilogue: LDS bounce (64 rows x 128 cols, pad 132) in 2 passes
    float* ft = (float*)&sm[0][0][0];
    float* Cf = (float*)Cm;
    #pragma unroll
    for (int pass = 0; pass < 2; ++pass) {
      __syncthreads();
      if ((wave >> 1) == pass) {
        #pragma unroll
        for (int m = 0; m < 4; ++m) {
          const int rl0 = m * 16 + (lane >> 4) * 4;     // 0..63 within pass
          #pragma unroll
          for (int n = 0; n < 4; ++n) {
            const int cl = wc + n * 16 + (lane & 15);   // 0..127
            float bc = biasCol ? biasCol[n0 + cl] : 0.f;
            #pragma unroll
            for (int r = 0; r < 4; ++r) {
              float val = acc[m][n][r] * scale + bc;
              if (biasRow) val += biasRow[m0 + pass * 64 + rl0 + r];
              ft[(rl0 + r) * 132 + cl] = val;
            }
          }
        }
      }
      __syncthreads();
      #pragma unroll
      for (int i = 0; i < 8; ++i) {
        int idx = i * 256 + tid;
        int rrow = idx >> 5, c4 = (idx & 31) << 2;
        float4 v = *(const float4*)&ft[rrow * 132 + c4];
        size_t gidx = (size_t)(m0 + pass * 64 + rrow) * ldc + (n0 + c4);
        if (Res) {
          const float4 rv = *(const float4*)&Res[(size_t)bz * sRes + gidx];
          v.x += rv.x; v.y += rv.y; v.z += rv.z; v.w += rv.w;
        }
        *(float4*)&Cf[(size_t)bz * sC + gidx] = v;
      }
    }
  }
}

// ---------------- in-place row softmax on bf16 scores ----------------
__global__ void softmax_rows(unsigned short* __restrict__ S) {
  // grid (HWP, G); one block per row of 4096
  size_t roff = ((size_t)blockIdx.y * HWP + blockIdx.x) * HWP;
  unsigned short* row = S + roff;
  const int tid = threadIdx.x;
  float v[16];
  s16x8 rlo = *(const s16x8*)&row[tid * 16];
  s16x8 rhi = *(const s16x8*)&row[tid * 16 + 8];
  #pragma unroll
  for (int j = 0; j < 8; ++j) {
    v[j] = bf2f((unsigned short)rlo[j]);
    v[8 + j] = bf2f((unsigned short)rhi[j]);
  }
  float mx = v[0];
  #pragma unroll
  for (int j = 1; j < 16; ++j) mx = fmaxf(mx, v[j]);
  #pragma unroll
  for (int o = 32; o; o >>= 1) mx = fmaxf(mx, __shfl_xor(mx, o));
  __shared__ float red[8];
  const int wv = tid >> 6;
  if ((tid & 63) == 0) red[wv] = mx;
  __syncthreads();
  mx = fmaxf(fmaxf(red[0], red[1]), fmaxf(red[2], red[3]));
  float s = 0.f;
  #pragma unroll
  for (int j = 0; j < 16; ++j) { v[j] = __expf(v[j] - mx); s += v[j]; }
  #pragma unroll
  for (int o = 32; o; o >>= 1) s += __shfl_xor(s, o);
  if ((tid & 63) == 0) red[4 + wv] = s;
  __syncthreads();
  s = red[4] + red[5] + red[6] + red[7];
  float inv = 1.f / s;
  #pragma unroll
  for (int j = 0; j < 8; ++j) {
    rlo[j] = (short)f2bf(v[j] * inv);
    rhi[j] = (short)f2bf(v[8 + j] * inv);
  }
  *(s16x8*)&row[tid * 16] = rlo;
  *(s16x8*)&row[tid * 16 + 8] = rhi;
}

extern "C" void kernel_launch(void* const* d_in, const int* in_sizes, int n_in,
                              void* d_out, int out_size, void* d_ws, size_t ws_size,
                              hipStream_t stream) {
  (void)in_sizes; (void)n_in; (void)out_size;
  const float* x   = (const float*)d_in[0];
  const float* nsc = (const float*)d_in[1];
  const float* nbi = (const float*)d_in[2];
  const float* wq  = (const float*)d_in[3];
  const float* bq  = (const float*)d_in[4];
  const float* wk  = (const float*)d_in[5];
  const float* bk  = (const float*)d_in[6];
  const float* wv  = (const float*)d_in[7];
  const float* bv  = (const float*)d_in[8];
  const float* wp  = (const float*)d_in[9];
  const float* bp  = (const float*)d_in[10];
  float* out = (float*)d_out;
  char* ws = (char*)d_ws;

  const size_t nW = (size_t)CCH * CCH;
  unsigned short* wb = (unsigned short*)ws;            // 2 MB
  float* bcat = (float*)(ws + 4 * nW * 2);             // 6 KB
  float* stats = bcat + 1536;                          // 2 KB
  const size_t o_h = 4 * nW * 2 + 16384;
  unsigned short* ht  = (unsigned short*)(ws + o_h);   // 32 MB  (b, p, 512)
  unsigned short* qkv = ht + (size_t)BATCH * HWP * CCH;        // 96 MB (b, p, 1536)
  unsigned short* vT  = qkv + (size_t)BATCH * HWP * 1536;      // 32 MB (b, c, p)
  unsigned short* Sb  = vT + (size_t)BATCH * CCH * HWP;        // G*32 MB
  unsigned short* ot  = ht;                            // alias: ht dead after QKV gemm
  const size_t o_S = o_h + ((size_t)BATCH * HWP * (CCH + 1536 + CCH)) * 2;
  const size_t sS1 = (size_t)HWP * HWP;
  int G = 8;
  while (G > 1 && o_S + (size_t)G * sS1 * 2 > ws_size) G >>= 1;

  const long long sHC   = (long long)HWP * CCH;        // 2M elements
  const long long sQKV  = (long long)HWP * 1536;

  cvt_w<<<dim3((unsigned)((nW + 255) / 256)), dim3(256), 0, stream>>>(
      wq, wk, wv, wp, bq, bk, bv, wb, bcat);
  gn_stats<<<dim3(BATCH * NG), dim3(256), 0, stream>>>(x, stats);
  gn_apply<<<dim3(HWP / 64, CCH / 64, BATCH), dim3(256), 0, stream>>>(x, stats, nsc, nbi, ht);

  // fused QKV: qkv[p][o] = sum_c h_t[p][c] wqkv[o][c] + bcat[o], o in [0,1536)
  gemm_nt<0><<<dim3(1536 / 128, HWP / 128, BATCH), dim3(256), 0, stream>>>(
      ht, wb, qkv, nullptr, bcat, nullptr,
      HWP, 1536, CCH, CCH, CCH, 1536, 1.f, 1, sHC, 0, sQKV, 0);

  transpose_v<<<dim3(HWP / 64, CCH / 64, BATCH), dim3(256), 0, stream>>>(qkv, vT);

  const float sc = 0.04419417382415922f;               // 512^-0.5
  for (int b0 = 0; b0 < BATCH; b0 += G) {
    // S[d][e] = scale * sum_c q[d][c] k[e][c]
    gemm_nt<1><<<dim3(HWP / 128, HWP / 128, G), dim3(256), 0, stream>>>(
        qkv + (size_t)b0 * sQKV, qkv + 512 + (size_t)b0 * sQKV, Sb,
        nullptr, nullptr, nullptr,
        HWP, HWP, CCH, 1536, 1536, HWP, sc, 1, sQKV, sQKV, (long long)HWP * HWP, 0);
    softmax_rows<<<dim3(HWP, G), dim3(256), 0, stream>>>(Sb);
    // o_t[d][c] = sum_e P[d][e] vT[c][e]
    gemm_nt<2><<<dim3(CCH / 128, HWP / 128, G), dim3(256), 0, stream>>>(
        Sb, vT + (size_t)b0 * sHC, ot + (size_t)b0 * sHC,
        nullptr, nullptr, nullptr,
        HWP, CCH, HWP, HWP, HWP, CCH, 1.f, 1, (long long)HWP * HWP, sHC, sHC, 0);
  }

  // final: out[o][p] = x[o][p] + bp[o] + sum_c wp[o][c] o_t[p][c]   (f32, coalesced epilogue)
  gemm_nt<3><<<dim3(HWP / 128, CCH / 128, BATCH), dim3(256), 0, stream>>>(
      wb + 3 * nW, ot, out, bp, nullptr, x,
      CCH, HWP, CCH, CCH, CCH, HWP, 1.f, 0, 0, sHC, sHC, sHC);
}